// Round 1
// baseline (559.538 us; speedup 1.0000x reference)
//
#include <hip/hip_runtime.h>
#include <math.h>

// Problem constants (fixed shapes from setup_inputs)
#define BI 128
#define BT 128
#define RR 36
#define WW 50
#define DD 256
#define NIMG (BI * RR)   // 4608 image row-vectors
#define NCAP (BT * WW)   // 6400 caption row-vectors
#define LAMB_INV 20.0f   // 1/0.05
#define EPSF 1e-6f

// Padded GEMM tile: S is 36x50, padded to 40x64 (zeros) so 256 threads map cleanly.
#define PRW 40           // padded rows
#define PCW 64           // padded cols
#define ASTR 68          // As row stride (floats); 68/4=17 odd -> uniform LDS bank-quad coverage
#define BSTR 68
#define PSTR 51          // P row stride (floats), odd -> conflict-light column access

// ---------------------------------------------------------------------------
// Kernel 1: inverse L2 norms of all img rows and cap rows -> d_ws (44 KB).
// One wave (64 lanes) per 256-float vector; each lane loads one float4.
// ---------------------------------------------------------------------------
__global__ __launch_bounds__(256) void norm_kernel(
    const float* __restrict__ imgs, const float* __restrict__ caps,
    float* __restrict__ invnorm)
{
    int gid  = blockIdx.x * 256 + threadIdx.x;
    int wave = gid >> 6;
    int lane = gid & 63;
    if (wave >= NIMG + NCAP) return;
    const float* src = (wave < NIMG) ? (imgs + (size_t)wave * DD)
                                     : (caps + (size_t)(wave - NIMG) * DD);
    const float4* s4 = (const float4*)src;
    float4 v = s4[lane];
    float ss = v.x * v.x + v.y * v.y + v.z * v.z + v.w * v.w;
#pragma unroll
    for (int off = 32; off > 0; off >>= 1) ss += __shfl_down(ss, off, 64);
    if (lane == 0) {
        float n = sqrtf(ss);
        invnorm[wave] = 1.0f / fmaxf(n, 1e-8f);  // matches x / clip(norm, 1e-8)
    }
}

// ---------------------------------------------------------------------------
// Kernel 2: one block (256 threads) per (i,j) pair.
//   Phase A: fp32 GEMM S = A_i . B_j^T via LDS k-tiles (KT=64), S in registers
//            (each thread owns rows {trow+8m}, cols {tcol+32n} -> 5x2 tile).
//   Phase B: Sinkhorn on P in LDS, 3 iterations, exact EPS placement as ref.
//   Phase C: out[i,j] = sum(S * P).
// ---------------------------------------------------------------------------
__global__ __launch_bounds__(256) void pair_kernel(
    const float* __restrict__ imgs, const float* __restrict__ caps,
    const int* __restrict__ img_lens, const int* __restrict__ cap_lens,
    const float* __restrict__ invnorm, float* __restrict__ out)
{
    __shared__ float As[PRW][ASTR];
    __shared__ float Bs[PCW][BSTR];
    __shared__ float Pm[RR][PSTR];
    __shared__ float rs[PRW];
    __shared__ float cs[PCW];
    __shared__ float red[4];
    __shared__ float bscale;

    const int pair = blockIdx.x;
    const int i = pair >> 7;         // consecutive blocks share i -> A_i L2 reuse
    const int j = pair & (BT - 1);
    const int tid = threadIdx.x;
    const int nr = img_lens[i];      // valid rows (<= 36)
    const int nc = cap_lens[j];      // valid cols (<= 50)
    const float inv_nr = 1.0f / (float)nr;
    const float inv_nc = 1.0f / (float)nc;

    const int trow = tid >> 5;       // 0..7
    const int tcol = tid & 31;       // 0..31

    float acc[5][2];
#pragma unroll
    for (int m = 0; m < 5; ++m)
#pragma unroll
        for (int n = 0; n < 2; ++n) acc[m][n] = 0.0f;

    const float4* imgs4 = (const float4*)(imgs + (size_t)i * RR * DD);
    const float4* caps4 = (const float4*)(caps + (size_t)j * WW * DD);
    const float* inA = invnorm + i * RR;
    const float* inB = invnorm + NIMG + j * WW;

    // ---- Phase A: GEMM over K=256 in 4 tiles of 64 ----
    for (int kt4 = 0; kt4 < DD / 4; kt4 += 16) {
        // stage A tile: 40 rows x 16 float4 (rows >=36 zero)
        for (int idx = tid; idx < PRW * 16; idx += 256) {
            int r = idx >> 4, k4 = idx & 15;
            float4 v = make_float4(0.f, 0.f, 0.f, 0.f);
            if (r < RR) {
                float4 t = imgs4[r * (DD / 4) + kt4 + k4];
                float s = inA[r];
                v.x = t.x * s; v.y = t.y * s; v.z = t.z * s; v.w = t.w * s;
            }
            *(float4*)&As[r][k4 * 4] = v;
        }
        // stage B tile: 64 rows x 16 float4 (rows >=50 zero)
        for (int idx = tid; idx < PCW * 16; idx += 256) {
            int w = idx >> 4, k4 = idx & 15;
            float4 v = make_float4(0.f, 0.f, 0.f, 0.f);
            if (w < WW) {
                float4 t = caps4[w * (DD / 4) + kt4 + k4];
                float s = inB[w];
                v.x = t.x * s; v.y = t.y * s; v.z = t.z * s; v.w = t.w * s;
            }
            *(float4*)&Bs[w][k4 * 4] = v;
        }
        __syncthreads();
#pragma unroll
        for (int k4 = 0; k4 < 16; ++k4) {
            float4 b0 = *(const float4*)&Bs[tcol][k4 * 4];
            float4 b1 = *(const float4*)&Bs[tcol + 32][k4 * 4];
#pragma unroll
            for (int m = 0; m < 5; ++m) {
                float4 a = *(const float4*)&As[trow + 8 * m][k4 * 4];
                acc[m][0] += a.x * b0.x + a.y * b0.y + a.z * b0.z + a.w * b0.w;
                acc[m][1] += a.x * b1.x + a.y * b1.y + a.z * b1.z + a.w * b1.w;
            }
        }
        __syncthreads();
    }

    // ---- Phase B: Sinkhorn ----
    // P0 = mask ? exp((s-1)*20) : 0 ; then P /= (sum + EPS)
    float p[5][2];
    float psum = 0.f;
#pragma unroll
    for (int m = 0; m < 5; ++m) {
        int r = trow + 8 * m;
#pragma unroll
        for (int n = 0; n < 2; ++n) {
            int c = tcol + 32 * n;
            float pv = 0.f;
            if (r < nr && c < nc) pv = __expf((acc[m][n] - 1.0f) * LAMB_INV);
            p[m][n] = pv;
            psum += pv;
        }
    }
#pragma unroll
    for (int off = 32; off > 0; off >>= 1) psum += __shfl_down(psum, off, 64);
    if ((tid & 63) == 0) red[tid >> 6] = psum;
    __syncthreads();
    if (tid == 0) bscale = 1.0f / (red[0] + red[1] + red[2] + red[3] + EPSF);
    __syncthreads();
    {
        float sc = bscale;
#pragma unroll
        for (int m = 0; m < 5; ++m) {
            int r = trow + 8 * m;
#pragma unroll
            for (int n = 0; n < 2; ++n) {
                int c = tcol + 32 * n;
                p[m][n] *= sc;
                if (r < RR && c < WW) Pm[r][c] = p[m][n];
            }
        }
    }
    __syncthreads();

    for (int it = 0; it < 3; ++it) {
        // row marginals: u = rowsum + EPS ; scale = (r<nr ? (1/nr)/u : 0)
        if (tid < PRW) {
            float s = 0.f;
            if (tid < RR) {
                for (int w = 0; w < WW; ++w) s += Pm[tid][w];
            }
            rs[tid] = (tid < nr) ? inv_nr / (s + EPSF) : 0.f;
        }
        __syncthreads();
#pragma unroll
        for (int m = 0; m < 5; ++m) {
            int r = trow + 8 * m;
            float f = rs[r];
#pragma unroll
            for (int n = 0; n < 2; ++n) {
                int c = tcol + 32 * n;
                p[m][n] *= f;
                if (r < RR && c < WW) Pm[r][c] = p[m][n];
            }
        }
        __syncthreads();
        // col marginals
        if (tid < PCW) {
            float s = 0.f;
            if (tid < WW) {
                for (int r = 0; r < RR; ++r) s += Pm[r][tid];
            }
            cs[tid] = (tid < nc) ? inv_nc / (s + EPSF) : 0.f;
        }
        __syncthreads();
#pragma unroll
        for (int m = 0; m < 5; ++m) {
            int r = trow + 8 * m;
#pragma unroll
            for (int n = 0; n < 2; ++n) {
                int c = tcol + 32 * n;
                p[m][n] *= cs[c];
                if (r < RR && c < WW) Pm[r][c] = p[m][n];
            }
        }
        __syncthreads();
    }

    // ---- Phase C: out = sum(S * P) (P already masked) ----
    float osum = 0.f;
#pragma unroll
    for (int m = 0; m < 5; ++m)
#pragma unroll
        for (int n = 0; n < 2; ++n) osum += acc[m][n] * p[m][n];
#pragma unroll
    for (int off = 32; off > 0; off >>= 1) osum += __shfl_down(osum, off, 64);
    if ((tid & 63) == 0) red[tid >> 6] = osum;
    __syncthreads();
    if (tid == 0) out[i * BT + j] = red[0] + red[1] + red[2] + red[3];
}

extern "C" void kernel_launch(void* const* d_in, const int* in_sizes, int n_in,
                              void* d_out, int out_size, void* d_ws, size_t ws_size,
                              hipStream_t stream) {
    const float* imgs     = (const float*)d_in[0];
    const float* caps     = (const float*)d_in[1];
    const int*   img_lens = (const int*)d_in[2];
    const int*   cap_lens = (const int*)d_in[3];
    float* out = (float*)d_out;
    float* invnorm = (float*)d_ws;   // 11008 floats = 44 KB

    int nvec = NIMG + NCAP;
    int nblocks = (nvec * 64 + 255) / 256;   // one wave per vector
    hipLaunchKernelGGL(norm_kernel, dim3(nblocks), dim3(256), 0, stream,
                       imgs, caps, invnorm);
    hipLaunchKernelGGL(pair_kernel, dim3(BI * BT), dim3(256), 0, stream,
                       imgs, caps, img_lens, cap_lens, invnorm, out);
}

// Round 2
// 234.846 us; speedup vs baseline: 2.3826x; 2.3826x over previous
//
#include <hip/hip_runtime.h>
#include <math.h>

// Problem constants (fixed shapes from setup_inputs)
#define BI 128
#define BT 128
#define RR 36
#define WW 50
#define DD 256
#define NIMG (BI * RR)   // 4608 image row-vectors
#define NCAP (BT * WW)   // 6400 caption row-vectors
#define LAMB_INV 20.0f   // 1/0.05
#define EPSF 1e-6f

typedef short  v8ss __attribute__((ext_vector_type(8)));
typedef __bf16 v8bf __attribute__((ext_vector_type(8)));
typedef float  v4f  __attribute__((ext_vector_type(4)));

// ---------------------------------------------------------------------------
// MFMA shim: handles either builtin signature (v8bf16 or v8i16 operands)
// via SFINAE so the source compiles regardless of ROCm's prototype choice.
// ---------------------------------------------------------------------------
template <typename V>
__device__ __forceinline__ auto mfma_impl(V a, V b, v4f c, int)
    -> decltype(__builtin_amdgcn_mfma_f32_16x16x32_bf16(a, b, c, 0, 0, 0)) {
    return __builtin_amdgcn_mfma_f32_16x16x32_bf16(a, b, c, 0, 0, 0);
}
template <typename V>
__device__ __forceinline__ v4f mfma_impl(V a, V b, v4f c, long) {
    v8ss a2 = __builtin_bit_cast(v8ss, a);
    v8ss b2 = __builtin_bit_cast(v8ss, b);
    return __builtin_amdgcn_mfma_f32_16x16x32_bf16(a2, b2, c, 0, 0, 0);
}
__device__ __forceinline__ v4f mfma_bf16(v8bf a, v8bf b, v4f c) {
    return mfma_impl(a, b, c, 0);
}

// fp32 -> bf16 RNE split helpers (hi + lo representation)
__device__ __forceinline__ unsigned short f2bf(float x) {
    unsigned int u = __builtin_bit_cast(unsigned int, x);
    u += 0x7fffu + ((u >> 16) & 1u);
    return (unsigned short)(u >> 16);
}
__device__ __forceinline__ float bf2f(unsigned short b) {
    unsigned int u = ((unsigned int)b) << 16;
    return __builtin_bit_cast(float, u);
}

// ---------------------------------------------------------------------------
// Kernel 1: inverse L2 norms of all img rows and cap rows -> d_ws (44 KB).
// ---------------------------------------------------------------------------
__global__ __launch_bounds__(256) void norm_kernel(
    const float* __restrict__ imgs, const float* __restrict__ caps,
    float* __restrict__ invnorm)
{
    int gid  = blockIdx.x * 256 + threadIdx.x;
    int wave = gid >> 6;
    int lane = gid & 63;
    if (wave >= NIMG + NCAP) return;
    const float* src = (wave < NIMG) ? (imgs + (size_t)wave * DD)
                                     : (caps + (size_t)(wave - NIMG) * DD);
    const float4* s4 = (const float4*)src;
    float4 v = s4[lane];
    float ss = v.x * v.x + v.y * v.y + v.z * v.z + v.w * v.w;
#pragma unroll
    for (int off = 32; off > 0; off >>= 1) ss += __shfl_down(ss, off, 64);
    if (lane == 0) {
        float n = sqrtf(ss);
        invnorm[wave] = 1.0f / fmaxf(n, 1e-8f);
    }
}

// ---------------------------------------------------------------------------
// Kernel 2: one block = 4 waves = 4 pairs (one i, four j). Split-bf16 MFMA
// GEMM (3 passes) with per-length tile pruning; Sinkhorn fully in registers
// via xor-shuffles on the MFMA C/D layout (col=lane&15, row=quad*4+reg).
// ---------------------------------------------------------------------------
__global__ __launch_bounds__(256) void pair_kernel(
    const float* __restrict__ imgs, const float* __restrict__ caps,
    const int* __restrict__ img_lens, const int* __restrict__ cap_lens,
    const float* __restrict__ invnorm, float* __restrict__ out)
{
    // Fragment-order staging buffers: [tile][lane-slot] of 16B chunks.
    __shared__ v8ss Ah[3 * 64];       // 3 M-tiles
    __shared__ v8ss Al[3 * 64];
    __shared__ v8ss Bh[4 * 4 * 64];   // 4 j x 4 N-tiles
    __shared__ v8ss Bl[4 * 4 * 64];

    const int tid  = threadIdx.x;
    const int lane = tid & 63;
    const int w    = tid >> 6;                 // wave id = jj (0..3)
    const int i    = blockIdx.x >> 5;          // 32 j-groups per i
    const int j0   = (blockIdx.x & 31) << 2;

    const int nr = img_lens[i];                // 1..36 (block-uniform)
    const int Ma = (nr + 15) >> 4;             // active M-tiles (1..3)
    const int nc = cap_lens[j0 + w];           // this wave's j (wave-uniform)
    const int Na = (nc + 15) >> 4;             // active N-tiles (1..4)

    v4f acc[3][4];
#pragma unroll
    for (int m = 0; m < 3; ++m)
#pragma unroll
        for (int n = 0; n < 4; ++n) acc[m][n] = (v4f){0.f, 0.f, 0.f, 0.f};

    const float* Abase = imgs + (size_t)i * RR * DD;
    const float* inA   = invnorm + i * RR;

    for (int ks = 0; ks < 8; ++ks) {           // K = 256 in chunks of 32
        const int k0 = ks << 5;
        // ---- stage A: Ma*64 chunks of 8 floats -> bf16 hi/lo ----
        for (int c = tid; c < Ma * 64; c += 256) {
            const int m   = c >> 6;
            const int t   = c & 63;
            const int rr  = t >> 2;            // row within tile
            const int kq  = t & 3;             // k-quad (8 elems)
            const int row = (m << 4) + rr;
            float4 f0 = make_float4(0.f, 0.f, 0.f, 0.f);
            float4 f1 = make_float4(0.f, 0.f, 0.f, 0.f);
            float  sc = 0.f;
            if (row < nr) {
                const float4* p = (const float4*)(Abase + row * DD + k0 + (kq << 3));
                f0 = p[0]; f1 = p[1];
                sc = inA[row];
            }
            v8ss h, l;
            float xs[8] = {f0.x, f0.y, f0.z, f0.w, f1.x, f1.y, f1.z, f1.w};
#pragma unroll
            for (int e = 0; e < 8; ++e) {
                float x = xs[e] * sc;
                unsigned short hb = f2bf(x);
                unsigned short lb = f2bf(x - bf2f(hb));
                h[e] = (short)hb; l[e] = (short)lb;
            }
            const int slot = (m << 6) + rr + (kq << 4);
            Ah[slot] = h; Al[slot] = l;
        }
        // ---- stage B for all 4 j's ----
#pragma unroll
        for (int jj = 0; jj < 4; ++jj) {
            const int j   = j0 + jj;
            const int ncj = cap_lens[j];
            const int Naj = (ncj + 15) >> 4;
            const float* Bbase = caps + (size_t)j * WW * DD;
            const float* inB   = invnorm + NIMG + j * WW;
            for (int c = tid; c < Naj * 64; c += 256) {
                const int n   = c >> 6;
                const int t   = c & 63;
                const int rr  = t >> 2;
                const int kq  = t & 3;
                const int row = (n << 4) + rr;
                float4 f0 = make_float4(0.f, 0.f, 0.f, 0.f);
                float4 f1 = make_float4(0.f, 0.f, 0.f, 0.f);
                float  sc = 0.f;
                if (row < ncj) {
                    const float4* p = (const float4*)(Bbase + row * DD + k0 + (kq << 3));
                    f0 = p[0]; f1 = p[1];
                    sc = inB[row];
                }
                v8ss h, l;
                float xs[8] = {f0.x, f0.y, f0.z, f0.w, f1.x, f1.y, f1.z, f1.w};
#pragma unroll
                for (int e = 0; e < 8; ++e) {
                    float x = xs[e] * sc;
                    unsigned short hb = f2bf(x);
                    unsigned short lb = f2bf(x - bf2f(hb));
                    h[e] = (short)hb; l[e] = (short)lb;
                }
                const int slot = (jj << 8) + (n << 6) + rr + (kq << 4);
                Bh[slot] = h; Bl[slot] = l;
            }
        }
        __syncthreads();
        // ---- MFMA: 3-pass split-bf16, pruned to active tiles ----
        v8bf ah[3], al[3];
#pragma unroll
        for (int m = 0; m < 3; ++m) if (m < Ma) {
            ah[m] = __builtin_bit_cast(v8bf, Ah[(m << 6) + lane]);
            al[m] = __builtin_bit_cast(v8bf, Al[(m << 6) + lane]);
        }
#pragma unroll
        for (int n = 0; n < 4; ++n) if (n < Na) {
            v8bf bh = __builtin_bit_cast(v8bf, Bh[(w << 8) + (n << 6) + lane]);
            v8bf bl = __builtin_bit_cast(v8bf, Bl[(w << 8) + (n << 6) + lane]);
#pragma unroll
            for (int m = 0; m < 3; ++m) if (m < Ma) {
                acc[m][n] = mfma_bf16(ah[m], bh, acc[m][n]);   // hi*hi
                acc[m][n] = mfma_bf16(al[m], bh, acc[m][n]);   // lo*hi
                acc[m][n] = mfma_bf16(ah[m], bl, acc[m][n]);   // hi*lo
            }
        }
        __syncthreads();
    }

    // ---- Sinkhorn, fully in registers ----
    // C/D layout: col = lane&15 (within N-tile), row = (lane>>4)*4 + reg.
    const int cl = lane & 15;
    const int rq = (lane >> 4) << 2;
    const float inv_nr = 1.0f / (float)nr;
    const float inv_nc = 1.0f / (float)nc;

    float P[3][4][4];
    float tot = 0.f;
#pragma unroll
    for (int m = 0; m < 3; ++m) if (m < Ma)
#pragma unroll
        for (int n = 0; n < 4; ++n) if (n < Na)
#pragma unroll
            for (int q = 0; q < 4; ++q) {
                const int row = (m << 4) + rq + q;
                const int col = (n << 4) + cl;
                float pv = 0.f;
                if (row < nr && col < nc)
                    pv = __expf((acc[m][n][q] - 1.0f) * LAMB_INV);
                P[m][n][q] = pv;
                tot += pv;
            }
#pragma unroll
    for (int off = 1; off < 64; off <<= 1) tot += __shfl_xor(tot, off, 64);
    {
        const float gsc = 1.0f / (tot + EPSF);
#pragma unroll
        for (int m = 0; m < 3; ++m) if (m < Ma)
#pragma unroll
            for (int n = 0; n < 4; ++n) if (n < Na)
#pragma unroll
                for (int q = 0; q < 4; ++q) P[m][n][q] *= gsc;
    }

#pragma unroll
    for (int it = 0; it < 3; ++it) {
        // row update: u = rowsum + EPS ; P *= (1/nr)/u  (invalid rows have P=0)
#pragma unroll
        for (int m = 0; m < 3; ++m) if (m < Ma)
#pragma unroll
            for (int q = 0; q < 4; ++q) {
                float rs = 0.f;
#pragma unroll
                for (int n = 0; n < 4; ++n) if (n < Na) rs += P[m][n][q];
                rs += __shfl_xor(rs, 1, 64);
                rs += __shfl_xor(rs, 2, 64);
                rs += __shfl_xor(rs, 4, 64);
                rs += __shfl_xor(rs, 8, 64);
                const float rsc = inv_nr / (rs + EPSF);
#pragma unroll
                for (int n = 0; n < 4; ++n) if (n < Na) P[m][n][q] *= rsc;
            }
        // col update
#pragma unroll
        for (int n = 0; n < 4; ++n) if (n < Na) {
            float cs = 0.f;
#pragma unroll
            for (int m = 0; m < 3; ++m) if (m < Ma)
#pragma unroll
                for (int q = 0; q < 4; ++q) cs += P[m][n][q];
            cs += __shfl_xor(cs, 16, 64);
            cs += __shfl_xor(cs, 32, 64);
            const float csc = inv_nc / (cs + EPSF);
#pragma unroll
            for (int m = 0; m < 3; ++m) if (m < Ma)
#pragma unroll
                for (int q = 0; q < 4; ++q) P[m][n][q] *= csc;
        }
    }

    // ---- output: sum(S * P) ----
    float osum = 0.f;
#pragma unroll
    for (int m = 0; m < 3; ++m) if (m < Ma)
#pragma unroll
        for (int n = 0; n < 4; ++n) if (n < Na)
#pragma unroll
            for (int q = 0; q < 4; ++q) osum += acc[m][n][q] * P[m][n][q];
#pragma unroll
    for (int off = 1; off < 64; off <<= 1) osum += __shfl_xor(osum, off, 64);
    if (lane == 0) out[i * BT + j0 + w] = osum;
}

extern "C" void kernel_launch(void* const* d_in, const int* in_sizes, int n_in,
                              void* d_out, int out_size, void* d_ws, size_t ws_size,
                              hipStream_t stream) {
    const float* imgs     = (const float*)d_in[0];
    const float* caps     = (const float*)d_in[1];
    const int*   img_lens = (const int*)d_in[2];
    const int*   cap_lens = (const int*)d_in[3];
    float* out = (float*)d_out;
    float* invnorm = (float*)d_ws;   // 11008 floats = 44 KB

    int nvec = NIMG + NCAP;
    int nblocks = (nvec * 64 + 255) / 256;
    hipLaunchKernelGGL(norm_kernel, dim3(nblocks), dim3(256), 0, stream,
                       imgs, caps, invnorm);
    hipLaunchKernelGGL(pair_kernel, dim3(BI * 32), dim3(256), 0, stream,
                       imgs, caps, img_lens, cap_lens, invnorm, out);
}

// Round 3
// 172.143 us; speedup vs baseline: 3.2504x; 1.3642x over previous
//
#include <hip/hip_runtime.h>
#include <math.h>

// Problem constants (fixed shapes from setup_inputs)
#define BI 128
#define BT 128
#define RR 36
#define WW 50
#define DD 256
#define LAMB_INV 20.0f   // 1/0.05
#define EPSF 1e-6f

#define A_TILES 3        // ceil(36/16)
#define B_TILES 4        // ceil(50/16)
#define KSTEPS 8         // 256 / 32
#define AROWS (BI * 48)  // virtual A rows incl. zero padding to 3 tiles
#define BROWS (BT * 64)  // virtual B rows incl. zero padding to 4 tiles
#define A_SLOTS (BI * A_TILES * KSTEPS * 64)  // 196608 x 16B = 3 MiB
#define B_SLOTS (BT * B_TILES * KSTEPS * 64)  // 262144 x 16B = 4 MiB
// d_ws layout: [Ah | Al | Bh | Bl] = 2*(3+4) MiB = 14,680,064 bytes

typedef short  v8ss __attribute__((ext_vector_type(8)));
typedef __bf16 v8bf __attribute__((ext_vector_type(8)));
typedef float  v4f  __attribute__((ext_vector_type(4)));

// MFMA shim: tolerate either builtin operand type (v8bf16 or v8i16).
template <typename V>
__device__ __forceinline__ auto mfma_impl(V a, V b, v4f c, int)
    -> decltype(__builtin_amdgcn_mfma_f32_16x16x32_bf16(a, b, c, 0, 0, 0)) {
    return __builtin_amdgcn_mfma_f32_16x16x32_bf16(a, b, c, 0, 0, 0);
}
template <typename V>
__device__ __forceinline__ v4f mfma_impl(V a, V b, v4f c, long) {
    v8ss a2 = __builtin_bit_cast(v8ss, a);
    v8ss b2 = __builtin_bit_cast(v8ss, b);
    return __builtin_amdgcn_mfma_f32_16x16x32_bf16(a2, b2, c, 0, 0, 0);
}
__device__ __forceinline__ v4f mfma_bf16(v8bf a, v8bf b, v4f c) {
    return mfma_impl(a, b, c, 0);
}

// fp32 -> bf16 RNE split helpers (hi + lo representation)
__device__ __forceinline__ unsigned short f2bf(float x) {
    unsigned int u = __builtin_bit_cast(unsigned int, x);
    u += 0x7fffu + ((u >> 16) & 1u);
    return (unsigned short)(u >> 16);
}
__device__ __forceinline__ float bf2f(unsigned short b) {
    unsigned int u = ((unsigned int)b) << 16;
    return __builtin_bit_cast(float, u);
}

// ---------------------------------------------------------------------------
// Kernel 1: normalize + split EVERY source row ONCE, writing bf16 hi/lo
// fragments in MFMA fragment order to global. One wave per virtual row
// (incl. pad rows, which write zeros so poisoned d_ws is fully initialized).
// Fragment layout (verified in R2): within a 16-row tile / 32-k chunk,
// slot lane = (row&15) + (k_quad<<4), elements e: k = k_quad*8 + e.
// ---------------------------------------------------------------------------
__global__ __launch_bounds__(256) void convert_kernel(
    const float* __restrict__ imgs, const float* __restrict__ caps,
    v8ss* __restrict__ Ah_g, v8ss* __restrict__ Al_g,
    v8ss* __restrict__ Bh_g, v8ss* __restrict__ Bl_g)
{
    const int gid  = blockIdx.x * 256 + threadIdx.x;
    const int wv   = gid >> 6;
    const int lane = gid & 63;

    const bool isA = wv < AROWS;
    int grp, r;
    const float* src;
    bool valid;
    if (isA) {
        grp = wv / 48; r = wv - grp * 48;
        src = imgs + ((size_t)grp * RR + r) * DD;
        valid = (r < RR);
    } else {
        int v = wv - AROWS;
        grp = v >> 6; r = v & 63;
        src = caps + ((size_t)grp * WW + r) * DD;
        valid = (r < WW);
    }

    float inv = 0.f;
    if (valid) {
        const float4* s4 = (const float4*)src;
        float4 x = s4[lane];
        float ss = x.x * x.x + x.y * x.y + x.z * x.z + x.w * x.w;
#pragma unroll
        for (int off = 1; off < 64; off <<= 1) ss += __shfl_xor(ss, off, 64);
        inv = 1.0f / fmaxf(sqrtf(ss), 1e-8f);
    }
    if (lane >= 32) return;   // 32 chunks of 8 elements per row

    const int ks = lane >> 2;      // k-step (0..7)
    const int kq = lane & 3;       // k-quad within step
    v8ss h, l;
    if (valid) {
        const float4* p = (const float4*)(src + lane * 8);
        float4 f0 = p[0], f1 = p[1];
        float xs[8] = {f0.x, f0.y, f0.z, f0.w, f1.x, f1.y, f1.z, f1.w};
#pragma unroll
        for (int e = 0; e < 8; ++e) {
            float x = xs[e] * inv;
            unsigned short hb = f2bf(x);
            unsigned short lb = f2bf(x - bf2f(hb));
            h[e] = (short)hb; l[e] = (short)lb;
        }
    } else {
#pragma unroll
        for (int e = 0; e < 8; ++e) { h[e] = 0; l[e] = 0; }
    }

    const int tile = r >> 4, rr = r & 15;
    if (isA) {
        size_t slot = ((size_t)(grp * A_TILES + tile) * KSTEPS + ks) * 64 + rr + (kq << 4);
        Ah_g[slot] = h; Al_g[slot] = l;
    } else {
        size_t slot = ((size_t)(grp * B_TILES + tile) * KSTEPS + ks) * 64 + rr + (kq << 4);
        Bh_g[slot] = h; Bl_g[slot] = l;
    }
}

// ---------------------------------------------------------------------------
// Kernel 2: one wave per (i,j) pair; 4 waves/block share i for L1 locality.
// No LDS, no __syncthreads. Fragments loaded straight from global
// (coalesced dwordx4: lane l -> base + l*16), double-buffered one k-step
// ahead. 3-pass split-bf16 MFMA, tiles pruned by valid lengths. Sinkhorn
// fully in registers via xor-shuffles on the C/D layout
// (col = lane&15, row = (lane>>4)*4 + reg).
// ---------------------------------------------------------------------------
__global__ __launch_bounds__(256) void pair_kernel(
    const v8ss* __restrict__ Ah_g, const v8ss* __restrict__ Al_g,
    const v8ss* __restrict__ Bh_g, const v8ss* __restrict__ Bl_g,
    const int* __restrict__ img_lens, const int* __restrict__ cap_lens,
    float* __restrict__ out)
{
    const int tid  = threadIdx.x;
    const int lane = tid & 63;
    const int w    = tid >> 6;
    const int i    = blockIdx.x >> 5;
    const int j    = ((blockIdx.x & 31) << 2) + w;

    const int nr = img_lens[i];
    const int nc = cap_lens[j];
    const int Ma = (nr + 15) >> 4;
    const int Na = (nc + 15) >> 4;

    const v8ss* Ah_b = Ah_g + (size_t)i * (A_TILES * KSTEPS * 64) + lane;
    const v8ss* Al_b = Al_g + (size_t)i * (A_TILES * KSTEPS * 64) + lane;
    const v8ss* Bh_b = Bh_g + (size_t)j * (B_TILES * KSTEPS * 64) + lane;
    const v8ss* Bl_b = Bl_g + (size_t)j * (B_TILES * KSTEPS * 64) + lane;

    v4f acc[3][4];
#pragma unroll
    for (int m = 0; m < 3; ++m)
#pragma unroll
        for (int n = 0; n < 4; ++n) acc[m][n] = (v4f){0.f, 0.f, 0.f, 0.f};

    v8bf ah[2][3], al[2][3], bh[2][4], bl[2][4];

    auto load_stage = [&](int ks, int buf) {
#pragma unroll
        for (int m = 0; m < 3; ++m) if (m < Ma) {
            ah[buf][m] = __builtin_bit_cast(v8bf, Ah_b[(m * KSTEPS + ks) * 64]);
            al[buf][m] = __builtin_bit_cast(v8bf, Al_b[(m * KSTEPS + ks) * 64]);
        }
#pragma unroll
        for (int n = 0; n < 4; ++n) if (n < Na) {
            bh[buf][n] = __builtin_bit_cast(v8bf, Bh_b[(n * KSTEPS + ks) * 64]);
            bl[buf][n] = __builtin_bit_cast(v8bf, Bl_b[(n * KSTEPS + ks) * 64]);
        }
    };
    auto do_mfma = [&](int buf) {
#pragma unroll
        for (int n = 0; n < 4; ++n) if (n < Na)
#pragma unroll
            for (int m = 0; m < 3; ++m) if (m < Ma) {
                acc[m][n] = mfma_bf16(ah[buf][m], bh[buf][n], acc[m][n]);  // hi*hi
                acc[m][n] = mfma_bf16(al[buf][m], bh[buf][n], acc[m][n]);  // lo*hi
                acc[m][n] = mfma_bf16(ah[buf][m], bl[buf][n], acc[m][n]);  // hi*lo
            }
    };

    load_stage(0, 0);
#pragma unroll
    for (int ks = 0; ks < KSTEPS; ++ks) {
        const int cur = ks & 1;
        if (ks + 1 < KSTEPS) load_stage(ks + 1, cur ^ 1);
        do_mfma(cur);
    }

    // ---- Sinkhorn, fully in registers ----
    const int cl = lane & 15;
    const int rq = (lane >> 4) << 2;
    const float inv_nr = 1.0f / (float)nr;
    const float inv_nc = 1.0f / (float)nc;

    float P[3][4][4];
    float tot = 0.f;
#pragma unroll
    for (int m = 0; m < 3; ++m) if (m < Ma)
#pragma unroll
        for (int n = 0; n < 4; ++n) if (n < Na)
#pragma unroll
            for (int q = 0; q < 4; ++q) {
                const int row = (m << 4) + rq + q;
                const int col = (n << 4) + cl;
                float pv = 0.f;
                if (row < nr && col < nc)
                    pv = __expf((acc[m][n][q] - 1.0f) * LAMB_INV);
                P[m][n][q] = pv;
                tot += pv;
            }
#pragma unroll
    for (int off = 1; off < 64; off <<= 1) tot += __shfl_xor(tot, off, 64);
    {
        const float gsc = 1.0f / (tot + EPSF);
#pragma unroll
        for (int m = 0; m < 3; ++m) if (m < Ma)
#pragma unroll
            for (int n = 0; n < 4; ++n) if (n < Na)
#pragma unroll
                for (int q = 0; q < 4; ++q) P[m][n][q] *= gsc;
    }

#pragma unroll
    for (int it = 0; it < 3; ++it) {
        // row update: u = rowsum + EPS ; P *= (1/nr)/u  (invalid rows keep P=0)
#pragma unroll
        for (int m = 0; m < 3; ++m) if (m < Ma)
#pragma unroll
            for (int q = 0; q < 4; ++q) {
                float rs = 0.f;
#pragma unroll
                for (int n = 0; n < 4; ++n) if (n < Na) rs += P[m][n][q];
                rs += __shfl_xor(rs, 1, 64);
                rs += __shfl_xor(rs, 2, 64);
                rs += __shfl_xor(rs, 4, 64);
                rs += __shfl_xor(rs, 8, 64);
                const float rsc = inv_nr / (rs + EPSF);
#pragma unroll
                for (int n = 0; n < 4; ++n) if (n < Na) P[m][n][q] *= rsc;
            }
        // col update
#pragma unroll
        for (int n = 0; n < 4; ++n) if (n < Na) {
            float cs = 0.f;
#pragma unroll
            for (int m = 0; m < 3; ++m) if (m < Ma)
#pragma unroll
                for (int q = 0; q < 4; ++q) cs += P[m][n][q];
            cs += __shfl_xor(cs, 16, 64);
            cs += __shfl_xor(cs, 32, 64);
            const float csc = inv_nc / (cs + EPSF);
#pragma unroll
            for (int m = 0; m < 3; ++m) if (m < Ma)
#pragma unroll
                for (int q = 0; q < 4; ++q) P[m][n][q] *= csc;
        }
    }

    // ---- output: sum(S * P) ----
    float osum = 0.f;
#pragma unroll
    for (int m = 0; m < 3; ++m) if (m < Ma)
#pragma unroll
        for (int n = 0; n < 4; ++n) if (n < Na)
#pragma unroll
            for (int q = 0; q < 4; ++q) osum += acc[m][n][q] * P[m][n][q];
#pragma unroll
    for (int off = 1; off < 64; off <<= 1) osum += __shfl_xor(osum, off, 64);
    if (lane == 0) out[i * BT + j] = osum;
}

extern "C" void kernel_launch(void* const* d_in, const int* in_sizes, int n_in,
                              void* d_out, int out_size, void* d_ws, size_t ws_size,
                              hipStream_t stream) {
    const float* imgs     = (const float*)d_in[0];
    const float* caps     = (const float*)d_in[1];
    const int*   img_lens = (const int*)d_in[2];
    const int*   cap_lens = (const int*)d_in[3];
    float* out = (float*)d_out;

    // workspace layout (14,680,064 bytes total)
    v8ss* Ah_g = (v8ss*)d_ws;
    v8ss* Al_g = Ah_g + A_SLOTS;
    v8ss* Bh_g = Al_g + A_SLOTS;
    v8ss* Bl_g = Bh_g + B_SLOTS;

    const int cblocks = (AROWS + BROWS) * 64 / 256;   // 3584
    hipLaunchKernelGGL(convert_kernel, dim3(cblocks), dim3(256), 0, stream,
                       imgs, caps, Ah_g, Al_g, Bh_g, Bl_g);
    hipLaunchKernelGGL(pair_kernel, dim3(BI * 32), dim3(256), 0, stream,
                       Ah_g, Al_g, Bh_g, Bl_g, img_lens, cap_lens, out);
}